// Round 11
// baseline (298.514 us; speedup 1.0000x reference)
//
#include <hip/hip_runtime.h>
#include <hip/hip_bf16.h>

typedef __hip_bfloat16 bf16h;
typedef short short8 __attribute__((ext_vector_type(8)));
typedef float floatx4 __attribute__((ext_vector_type(4)));

__device__ __forceinline__ float bfu2f(unsigned int u) {
    return __uint_as_float((u & 0xffffu) << 16);
}
__device__ __forceinline__ float bfhi2f(unsigned int u) {
    return __uint_as_float(u & 0xffff0000u);
}
__device__ __forceinline__ unsigned short f2bfu(float f) {
    bf16h b = __float2bfloat16(f);  // RNE
    return *(unsigned short*)&b;
}

// ---------------- prep: detect dtypes, zero cnt, W -> MFMA bf16 hi/lo fragments, bias fp32 ----
// W fragment layout (B-operand, 16x16x32): idx = ((c*4+kk)*64 + lane)*8 + j
//   holds W[k = kk*32 + (lane>>4)*8 + j][n = c*16 + (lane&15)]
__global__ __launch_bounds__(256) void k_prep(const void* __restrict__ x,
                                              const int* __restrict__ ei,
                                              const void* __restrict__ W1, const void* __restrict__ b1,
                                              const void* __restrict__ W2, const void* __restrict__ b2,
                                              int* __restrict__ flagE, int* __restrict__ flagX,
                                              int* __restrict__ cnt,
                                              unsigned short* __restrict__ W1h, unsigned short* __restrict__ W1l,
                                              unsigned short* __restrict__ W2h, unsigned short* __restrict__ W2l,
                                              float* __restrict__ bfv1, float* __restrict__ bfv2, int n) {
    int t = threadIdx.x;
    __shared__ int sIsB;
    if (t < 64) {  // per-block local bf16-vs-fp32 detection on x
        unsigned int w = ((const unsigned int*)x)[t];
        unsigned int ef = (w >> 7) & 0xFFu;
        unsigned long long b = __ballot(ef >= 0x76u && ef <= 0x82u);
        if (t == 0) sIsB = (__popcll(b) >= 40) ? 1 : 0;
    }
    __syncthreads();
    bool isb = sIsB != 0;

    if (blockIdx.x == 0 && t < 64) {  // edge dtype: int64 => all odd words zero
        int v = ei[2 * t + 1];
        unsigned long long b = __ballot(v == 0);
        if (t == 0) { *flagE = (b == ~0ull) ? 1 : 0; *flagX = sIsB; }
    }

    int gsz = gridDim.x * 256;
    int gid = blockIdx.x * 256 + t;
    for (int i = gid; i < n; i += gsz) cnt[i] = 0;
    for (int i = gid; i < 16384; i += gsz) {
        int c  = i >> 11;
        int kk = (i >> 9) & 3;
        int ln = (i >> 3) & 63;
        int j  = i & 7;
        int k    = kk * 32 + (ln >> 4) * 8 + j;
        int ncol = c * 16 + (ln & 15);
        int src  = k * 128 + ncol;
        float v1 = isb ? bfu2f(((const unsigned short*)W1)[src]) : ((const float*)W1)[src];
        float v2 = isb ? bfu2f(((const unsigned short*)W2)[src]) : ((const float*)W2)[src];
        unsigned short h1 = f2bfu(v1), h2 = f2bfu(v2);
        W1h[i] = h1; W1l[i] = f2bfu(v1 - bfu2f(h1));
        W2h[i] = h2; W2l[i] = f2bfu(v2 - bfu2f(h2));
    }
    if (gid < 128) {
        bfv1[gid] = isb ? bfu2f(((const unsigned short*)b1)[gid]) : ((const float*)b1)[gid];
        bfv2[gid] = isb ? bfu2f(((const unsigned short*)b2)[gid]) : ((const float*)b2)[gid];
    }
}

// ---------------- CSR build ----------------

// 1 edge/thread (latency-bound scatter: maximize waves, not ILP — R10 lesson)
__global__ void k_count(const int* __restrict__ ei, const int* __restrict__ flag,
                        int* __restrict__ cnt, int e, int n) {
    int i = blockIdx.x * 256 + threadIdx.x;
    if (i >= e) return;
    int st = (*flag) ? 2 : 1;
    int d = ei[(size_t)e * st + (size_t)i * st];
    if (d >= 0 && d < n) atomicAdd(&cnt[d], 1);
}

// scan phase 1: per-block (256-elem) partial sums
__global__ __launch_bounds__(256) void k_bsum(const int* __restrict__ cnt,
                                              int* __restrict__ part, int n) {
    int t = threadIdx.x;
    int i = blockIdx.x * 256 + t;
    int v = (i < n) ? cnt[i] : 0;
#pragma unroll
    for (int m = 1; m < 64; m <<= 1) v += __shfl_xor(v, m, 64);
    __shared__ int ws[4];
    if ((t & 63) == 0) ws[t >> 6] = v;
    __syncthreads();
    if (t == 0) part[blockIdx.x] = ws[0] + ws[1] + ws[2] + ws[3];
}

// scan phase 2: single-wave exclusive scan over nb partials
__global__ void k_pscan(const int* __restrict__ part, int* __restrict__ ppre, int nb) {
    int lane = threadIdx.x;  // 64 threads
    int carry = 0;
    for (int base = 0; base < nb; base += 64) {
        int i = base + lane;
        int v = (i < nb) ? part[i] : 0;
        int incl = v;
#pragma unroll
        for (int d = 1; d < 64; d <<= 1) {
            int u = __shfl_up(incl, d, 64);
            if (lane >= d) incl += u;
        }
        if (i < nb) ppre[i] = carry + incl - v;
        carry += __shfl(incl, 63, 64);
    }
}

// scan phase 3: block-local scan + prefix, write off/cur/dinv (+off[n])
__global__ __launch_bounds__(256) void k_bscan(const int* __restrict__ cnt,
                                               const int* __restrict__ ppre,
                                               int* __restrict__ off, int* __restrict__ cur,
                                               float* __restrict__ dinv, int n) {
    int t = threadIdx.x;
    int lane = t & 63, wid = t >> 6;
    int i = blockIdx.x * 256 + t;
    int v = (i < n) ? cnt[i] : 0;
    int incl = v;
#pragma unroll
    for (int d = 1; d < 64; d <<= 1) {
        int u = __shfl_up(incl, d, 64);
        if (lane >= d) incl += u;
    }
    __shared__ int ws[4], wo[4];
    if (lane == 63) ws[wid] = incl;
    __syncthreads();
    if (t == 0) {
        int s = 0;
#pragma unroll
        for (int k = 0; k < 4; ++k) { wo[k] = s; s += ws[k]; }
    }
    __syncthreads();
    int excl = ppre[blockIdx.x] + wo[wid] + incl - v;
    if (i < n) {
        off[i] = excl;
        cur[i] = excl;
        dinv[i] = rsqrtf((float)v + 1.0f);
        if (i == n - 1) off[n] = excl + v;
    }
}

// 1 edge/thread; 4B record (src only — weights eliminated algebraically)
__global__ void k_fill(const int* __restrict__ ei, const int* __restrict__ flag,
                       int* __restrict__ cur, int* __restrict__ csrc, int e, int n) {
    int i = blockIdx.x * 256 + threadIdx.x;
    if (i >= e) return;
    int st = (*flag) ? 2 : 1;
    int s = ei[(size_t)i * st];
    int d = ei[(size_t)e * st + (size_t)i * st];
    if (s < 0 || s >= n || d < 0 || d >= n) return;
    int pos = atomicAdd(&cur[d], 1);
    csrc[pos] = s;
}

// ---------------- scale: Xb[row] = bf16(dinv[row] * x[row]) ----
__global__ __launch_bounds__(256) void k_scale(const void* __restrict__ x,
                                               const int* __restrict__ flagX,
                                               const float* __restrict__ dinv,
                                               unsigned int* __restrict__ Xb, int n) {
    bool isb = *flagX != 0;
    int total = n * 64;
    int gsz = gridDim.x * 256;
    for (int i = blockIdx.x * 256 + threadIdx.x; i < total; i += gsz) {
        float d = dinv[i >> 6];
        float lo, hi;
        if (isb) {
            unsigned int v = ((const unsigned int*)x)[i];
            lo = bfu2f(v); hi = bfhi2f(v);
        } else {
            float2 v = ((const float2*)x)[i];
            lo = v.x; hi = v.y;
        }
        Xb[i] = ((unsigned int)f2bfu(d * hi) << 16) | f2bfu(d * lo);
    }
}

// ---------------- Aggregate: out[v] = dinv[v] * (sum_{s in N(v)} Xb[s] + Xb[v]) ----
// One wave/node; 4 groups x 16 lanes; each group loads a full 256B row (uint4/lane);
// unroll 4 => 16 rows in flight per wave. Unweighted sum (rows pre-scaled).
__global__ __launch_bounds__(256) void k_agg(const unsigned int* __restrict__ Xb,
                                             const int* __restrict__ off,
                                             const int* __restrict__ csrc,
                                             const float* __restrict__ dinv,
                                             float* __restrict__ outf, int n) {
    int node = blockIdx.x * 4 + (threadIdx.x >> 6);
    if (node >= n) return;
    int lane = threadIdx.x & 63;
    int g = lane >> 4;    // group 0..3
    int l = lane & 15;    // lane in group
    int col = l * 4;      // uint index: 16 lanes x uint4 = full 128-feature row
    int beg = off[node], end = off[node + 1];
    int nm1 = n - 1;
    float acc[8] = {0.f, 0.f, 0.f, 0.f, 0.f, 0.f, 0.f, 0.f};
    for (int j = beg; j < end; j += 16) {
#pragma unroll
        for (int k = 0; k < 4; ++k) {
            int jj = j + k * 4 + g;
            bool ok = jj < end;
            int s = ok ? csrc[jj] : node;
            float w = ok ? 1.f : 0.f;
            s = min(max(s, 0), nm1);
            uint4 v = *(const uint4*)(Xb + (size_t)s * 64 + col);
            acc[0] += w * bfu2f(v.x);  acc[1] += w * bfhi2f(v.x);
            acc[2] += w * bfu2f(v.y);  acc[3] += w * bfhi2f(v.y);
            acc[4] += w * bfu2f(v.z);  acc[5] += w * bfhi2f(v.z);
            acc[6] += w * bfu2f(v.w);  acc[7] += w * bfhi2f(v.w);
        }
    }
#pragma unroll
    for (int i = 0; i < 8; ++i) {
        acc[i] += __shfl_xor(acc[i], 16, 64);
        acc[i] += __shfl_xor(acc[i], 32, 64);
    }
    if (g == 0) {
        uint4 v = *(const uint4*)(Xb + (size_t)node * 64 + col);  // self row (pre-scaled)
        acc[0] += bfu2f(v.x);  acc[1] += bfhi2f(v.x);
        acc[2] += bfu2f(v.y);  acc[3] += bfhi2f(v.y);
        acc[4] += bfu2f(v.z);  acc[5] += bfhi2f(v.z);
        acc[6] += bfu2f(v.w);  acc[7] += bfhi2f(v.w);
        float wd = dinv[node];
        float* po = outf + (size_t)node * 128 + l * 8;
        *(float4*)(po)     = make_float4(wd * acc[0], wd * acc[1], wd * acc[2], wd * acc[3]);
        *(float4*)(po + 4) = make_float4(wd * acc[4], wd * acc[5], wd * acc[6], wd * acc[7]);
    }
}

// ---------------- MFMA GEMM: out = relu(A_f32 @ W + b), split-precision bf16 ----
// D = Ah*Wh + Al*Wh + Ah*Wl. Wave: 16 rows x 128 cols; block = 64 rows. No LDS.
// SCALED_BF16: out = bf16(dinv[row] * relu(...)) — feeds next layer's gather table.
template <bool SCALED_BF16>
__global__ __launch_bounds__(256) void k_gemm_mfma(const float* __restrict__ A,
                                                   const unsigned short* __restrict__ Wh,
                                                   const unsigned short* __restrict__ Wl,
                                                   const float* __restrict__ bias,
                                                   const float* __restrict__ dinv,
                                                   void* __restrict__ out, int n) {
    int t = threadIdx.x;
    int wv = t >> 6, lane = t & 63;
    int quad = lane >> 4, l16 = lane & 15;
    int rowBase = blockIdx.x * 64 + wv * 16;
    int m = rowBase + l16;
    size_t arow = (size_t)min(m, n - 1) * 128;
    bool mok = m < n;

    floatx4 acc[8];
#pragma unroll
    for (int c = 0; c < 8; ++c) acc[c] = (floatx4){0.f, 0.f, 0.f, 0.f};

#pragma unroll
    for (int kk = 0; kk < 4; ++kk) {
        const float* ap = A + arow + kk * 32 + quad * 8;
        float4 a0 = mok ? *(const float4*)(ap) : make_float4(0.f, 0.f, 0.f, 0.f);
        float4 a1 = mok ? *(const float4*)(ap + 4) : make_float4(0.f, 0.f, 0.f, 0.f);
        float av[8] = {a0.x, a0.y, a0.z, a0.w, a1.x, a1.y, a1.z, a1.w};
        short8 ah, al;
#pragma unroll
        for (int j = 0; j < 8; ++j) {
            unsigned short h = f2bfu(av[j]);
            ah[j] = (short)h;
            al[j] = (short)f2bfu(av[j] - bfu2f(h));
        }
#pragma unroll
        for (int c = 0; c < 8; ++c) {
            int fo = ((c * 4 + kk) * 64 + lane) * 8;
            short8 bh = *(const short8*)(Wh + fo);
            short8 bl = *(const short8*)(Wl + fo);
            acc[c] = __builtin_amdgcn_mfma_f32_16x16x32_bf16(ah, bh, acc[c], 0, 0, 0);
            acc[c] = __builtin_amdgcn_mfma_f32_16x16x32_bf16(al, bh, acc[c], 0, 0, 0);
            acc[c] = __builtin_amdgcn_mfma_f32_16x16x32_bf16(ah, bl, acc[c], 0, 0, 0);
        }
    }

    // epilogue: C/D layout col = lane&15, row = quad*4 + reg  [m89-verified]
#pragma unroll
    for (int c = 0; c < 8; ++c) {
        int ncol = c * 16 + l16;
        float bv = bias[ncol];
#pragma unroll
        for (int r = 0; r < 4; ++r) {
            int row = rowBase + quad * 4 + r;
            if (row < n) {
                float o = fmaxf(acc[c][r] + bv, 0.f);
                if constexpr (SCALED_BF16) {
                    ((unsigned short*)out)[(size_t)row * 128 + ncol] = f2bfu(o * dinv[row]);
                } else {
                    ((float*)out)[(size_t)row * 128 + ncol] = o;
                }
            }
        }
    }
}

extern "C" void kernel_launch(void* const* d_in, const int* in_sizes, int n_in,
                              void* d_out, int out_size, void* d_ws, size_t ws_size,
                              hipStream_t stream) {
    const int n = in_sizes[0] / 128;
    const int e = in_sizes[1] / 2;
    const void* x = d_in[0];
    const int* ei = (const int*)d_in[1];

    char* w = (char*)d_ws;
    size_t o = 0;
    auto alloc = [&](size_t bytes) -> char* {
        char* p = w + o;
        o += (bytes + 255) & ~(size_t)255;
        return p;
    };
    const int nb = (n + 255) / 256;  // scan blocks
    int* flagE = (int*)alloc(4);
    int* flagX = (int*)alloc(4);
    int* cnt   = (int*)alloc((size_t)n * 4);
    int* off   = (int*)alloc((size_t)(n + 1) * 4);
    int* cur   = (int*)alloc((size_t)n * 4);
    float* dinv  = (float*)alloc((size_t)n * 4);
    int* part  = (int*)alloc((size_t)nb * 4);
    int* ppre  = (int*)alloc((size_t)nb * 4);
    int* csrc  = (int*)alloc((size_t)e * 4);  // 4B edge records
    unsigned short* W1h = (unsigned short*)alloc(16384 * 2);
    unsigned short* W1l = (unsigned short*)alloc(16384 * 2);
    unsigned short* W2h = (unsigned short*)alloc(16384 * 2);
    unsigned short* W2l = (unsigned short*)alloc(16384 * 2);
    float* bf1 = (float*)alloc(128 * 4);
    float* bf2 = (float*)alloc(128 * 4);
    unsigned int* Xb = (unsigned int*)alloc((size_t)n * 64 * 4);  // pre-scaled bf16 table
    float* B1 = (float*)alloc((size_t)n * 128 * 4);               // fp32 agg output
    (void)ws_size;  // ~42 MB

    k_prep<<<256, 256, 0, stream>>>(x, ei, d_in[2], d_in[3], d_in[4], d_in[5],
                                    flagE, flagX, cnt, W1h, W1l, W2h, W2l, bf1, bf2, n);
    int ec = (e + 255) / 256;
    k_count<<<ec, 256, 0, stream>>>(ei, flagE, cnt, e, n);
    k_bsum<<<nb, 256, 0, stream>>>(cnt, part, n);
    k_pscan<<<1, 64, 0, stream>>>(part, ppre, nb);
    k_bscan<<<nb, 256, 0, stream>>>(cnt, ppre, off, cur, dinv, n);
    k_fill<<<ec, 256, 0, stream>>>(ei, flagE, cur, csrc, e, n);
    k_scale<<<2048, 256, 0, stream>>>(x, flagX, dinv, Xb, n);

    int gm = (n + 63) / 64;
    int ga = (n + 3) / 4;
    // layer 1: B1 = dinv*(agg Xb); Xb <- bf16(dinv * relu(B1 @ W1 + b1))
    k_agg<<<ga, 256, 0, stream>>>(Xb, off, csrc, dinv, B1, n);
    k_gemm_mfma<true><<<gm, 256, 0, stream>>>(B1, W1h, W1l, bf1, dinv, Xb, n);
    // layer 2: B1 = dinv*(agg Xb); d_out(fp32) = relu(B1 @ W2 + b2)
    k_agg<<<ga, 256, 0, stream>>>(Xb, off, csrc, dinv, B1, n);
    k_gemm_mfma<false><<<gm, 256, 0, stream>>>(B1, W2h, W2l, bf2, dinv, d_out, n);
}

// Round 12
// 283.203 us; speedup vs baseline: 1.0541x; 1.0541x over previous
//
#include <hip/hip_runtime.h>
#include <hip/hip_bf16.h>

typedef __hip_bfloat16 bf16h;
typedef short short8 __attribute__((ext_vector_type(8)));
typedef float floatx4 __attribute__((ext_vector_type(4)));

__device__ __forceinline__ float bfu2f(unsigned int u) {
    return __uint_as_float((u & 0xffffu) << 16);
}
__device__ __forceinline__ float bfhi2f(unsigned int u) {
    return __uint_as_float(u & 0xffff0000u);
}
__device__ __forceinline__ unsigned short f2bfu(float f) {
    bf16h b = __float2bfloat16(f);  // RNE
    return *(unsigned short*)&b;
}

// ---------------- prep: detect dtypes, zero cnt, W -> MFMA bf16 hi/lo fragments, bias fp32 ----
__global__ __launch_bounds__(256) void k_prep(const void* __restrict__ x,
                                              const int* __restrict__ ei,
                                              const void* __restrict__ W1, const void* __restrict__ b1,
                                              const void* __restrict__ W2, const void* __restrict__ b2,
                                              int* __restrict__ flagE, int* __restrict__ flagX,
                                              int* __restrict__ cnt,
                                              unsigned short* __restrict__ W1h, unsigned short* __restrict__ W1l,
                                              unsigned short* __restrict__ W2h, unsigned short* __restrict__ W2l,
                                              float* __restrict__ bfv1, float* __restrict__ bfv2, int n) {
    int t = threadIdx.x;
    __shared__ int sIsB;
    if (t < 64) {  // per-block local bf16-vs-fp32 detection on x
        unsigned int w = ((const unsigned int*)x)[t];
        unsigned int ef = (w >> 7) & 0xFFu;
        unsigned long long b = __ballot(ef >= 0x76u && ef <= 0x82u);
        if (t == 0) sIsB = (__popcll(b) >= 40) ? 1 : 0;
    }
    __syncthreads();
    bool isb = sIsB != 0;

    if (blockIdx.x == 0 && t < 64) {  // edge dtype: int64 => all odd words zero
        int v = ei[2 * t + 1];
        unsigned long long b = __ballot(v == 0);
        if (t == 0) { *flagE = (b == ~0ull) ? 1 : 0; *flagX = sIsB; }
    }

    int gsz = gridDim.x * 256;
    int gid = blockIdx.x * 256 + t;
    for (int i = gid; i < n; i += gsz) cnt[i] = 0;
    for (int i = gid; i < 16384; i += gsz) {
        int c  = i >> 11;
        int kk = (i >> 9) & 3;
        int ln = (i >> 3) & 63;
        int j  = i & 7;
        int k    = kk * 32 + (ln >> 4) * 8 + j;
        int ncol = c * 16 + (ln & 15);
        int src  = k * 128 + ncol;
        float v1 = isb ? bfu2f(((const unsigned short*)W1)[src]) : ((const float*)W1)[src];
        float v2 = isb ? bfu2f(((const unsigned short*)W2)[src]) : ((const float*)W2)[src];
        unsigned short h1 = f2bfu(v1), h2 = f2bfu(v2);
        W1h[i] = h1; W1l[i] = f2bfu(v1 - bfu2f(h1));
        W2h[i] = h2; W2l[i] = f2bfu(v2 - bfu2f(h2));
    }
    if (gid < 128) {
        bfv1[gid] = isb ? bfu2f(((const unsigned short*)b1)[gid]) : ((const float*)b1)[gid];
        bfv2[gid] = isb ? bfu2f(((const unsigned short*)b2)[gid]) : ((const float*)b2)[gid];
    }
}

// ---------------- CSR build, XCD dst-partitioned ----------------
// blockIdx%8 selects a dst-range; groups of 8 consecutive blocks share one
// 256-edge chunk. All stores/atomics for a dst-range issue from one XCD
// (blockIdx%8 -> XCD round-robin heuristic) => L2 write-combining works.

__global__ void k_count(const int* __restrict__ ei, const int* __restrict__ flag,
                        int* __restrict__ cnt, int e, int n, int rpx) {
    int xcd = blockIdx.x & 7;
    int i = (blockIdx.x >> 3) * 256 + threadIdx.x;
    if (i >= e) return;
    int st = (*flag) ? 2 : 1;
    int d = ei[(size_t)e * st + (size_t)i * st];
    int lo = xcd * rpx, hi = min(n, lo + rpx);
    if (d >= lo && d < hi) atomicAdd(&cnt[d], 1);
}

// scan phase 1: per-block (256-elem) partial sums
__global__ __launch_bounds__(256) void k_bsum(const int* __restrict__ cnt,
                                              int* __restrict__ part, int n) {
    int t = threadIdx.x;
    int i = blockIdx.x * 256 + t;
    int v = (i < n) ? cnt[i] : 0;
#pragma unroll
    for (int m = 1; m < 64; m <<= 1) v += __shfl_xor(v, m, 64);
    __shared__ int ws[4];
    if ((t & 63) == 0) ws[t >> 6] = v;
    __syncthreads();
    if (t == 0) part[blockIdx.x] = ws[0] + ws[1] + ws[2] + ws[3];
}

// scan phase 2: single-wave exclusive scan over nb partials
__global__ void k_pscan(const int* __restrict__ part, int* __restrict__ ppre, int nb) {
    int lane = threadIdx.x;  // 64 threads
    int carry = 0;
    for (int base = 0; base < nb; base += 64) {
        int i = base + lane;
        int v = (i < nb) ? part[i] : 0;
        int incl = v;
#pragma unroll
        for (int d = 1; d < 64; d <<= 1) {
            int u = __shfl_up(incl, d, 64);
            if (lane >= d) incl += u;
        }
        if (i < nb) ppre[i] = carry + incl - v;
        carry += __shfl(incl, 63, 64);
    }
}

// scan phase 3: block-local scan + prefix, write off/cur/dinv (+off[n])
__global__ __launch_bounds__(256) void k_bscan(const int* __restrict__ cnt,
                                               const int* __restrict__ ppre,
                                               int* __restrict__ off, int* __restrict__ cur,
                                               float* __restrict__ dinv, int n) {
    int t = threadIdx.x;
    int lane = t & 63, wid = t >> 6;
    int i = blockIdx.x * 256 + t;
    int v = (i < n) ? cnt[i] : 0;
    int incl = v;
#pragma unroll
    for (int d = 1; d < 64; d <<= 1) {
        int u = __shfl_up(incl, d, 64);
        if (lane >= d) incl += u;
    }
    __shared__ int ws[4], wo[4];
    if (lane == 63) ws[wid] = incl;
    __syncthreads();
    if (t == 0) {
        int s = 0;
#pragma unroll
        for (int k = 0; k < 4; ++k) { wo[k] = s; s += ws[k]; }
    }
    __syncthreads();
    int excl = ppre[blockIdx.x] + wo[wid] + incl - v;
    if (i < n) {
        off[i] = excl;
        cur[i] = excl;
        dinv[i] = rsqrtf((float)v + 1.0f);
        if (i == n - 1) off[n] = excl + v;
    }
}

// XCD dst-partitioned fill; 4B record (src only)
__global__ void k_fill(const int* __restrict__ ei, const int* __restrict__ flag,
                       int* __restrict__ cur, int* __restrict__ csrc,
                       int e, int n, int rpx) {
    int xcd = blockIdx.x & 7;
    int i = (blockIdx.x >> 3) * 256 + threadIdx.x;
    if (i >= e) return;
    int st = (*flag) ? 2 : 1;
    int d = ei[(size_t)e * st + (size_t)i * st];
    int lo = xcd * rpx, hi = min(n, lo + rpx);
    if (d < lo || d >= hi) return;
    int s = ei[(size_t)i * st];
    if (s < 0 || s >= n) return;
    int pos = atomicAdd(&cur[d], 1);
    csrc[pos] = s;
}

// ---------------- scale: Xb[row] = bf16(dinv[row] * x[row]) ----
__global__ __launch_bounds__(256) void k_scale(const void* __restrict__ x,
                                               const int* __restrict__ flagX,
                                               const float* __restrict__ dinv,
                                               unsigned int* __restrict__ Xb, int n) {
    bool isb = *flagX != 0;
    int total = n * 64;
    int gsz = gridDim.x * 256;
    for (int i = blockIdx.x * 256 + threadIdx.x; i < total; i += gsz) {
        float d = dinv[i >> 6];
        float lo, hi;
        if (isb) {
            unsigned int v = ((const unsigned int*)x)[i];
            lo = bfu2f(v); hi = bfhi2f(v);
        } else {
            float2 v = ((const float2*)x)[i];
            lo = v.x; hi = v.y;
        }
        Xb[i] = ((unsigned int)f2bfu(d * hi) << 16) | f2bfu(d * lo);
    }
}

// ---------------- Aggregate: out[v] = dinv[v] * (sum_{s in N(v)} Xb[s] + Xb[v]) ----
// One wave/node; 4 groups x 16 lanes; uint4/lane; 16 rows in flight per wave.
__global__ __launch_bounds__(256) void k_agg(const unsigned int* __restrict__ Xb,
                                             const int* __restrict__ off,
                                             const int* __restrict__ csrc,
                                             const float* __restrict__ dinv,
                                             float* __restrict__ outf, int n) {
    int node = blockIdx.x * 4 + (threadIdx.x >> 6);
    if (node >= n) return;
    int lane = threadIdx.x & 63;
    int g = lane >> 4;    // group 0..3
    int l = lane & 15;    // lane in group
    int col = l * 4;      // uint index: 16 lanes x uint4 = full 128-feature row
    int beg = off[node], end = off[node + 1];
    int nm1 = n - 1;
    float acc[8] = {0.f, 0.f, 0.f, 0.f, 0.f, 0.f, 0.f, 0.f};
    for (int j = beg; j < end; j += 16) {
#pragma unroll
        for (int k = 0; k < 4; ++k) {
            int jj = j + k * 4 + g;
            bool ok = jj < end;
            int s = ok ? csrc[jj] : node;
            float w = ok ? 1.f : 0.f;
            s = min(max(s, 0), nm1);
            uint4 v = *(const uint4*)(Xb + (size_t)s * 64 + col);
            acc[0] += w * bfu2f(v.x);  acc[1] += w * bfhi2f(v.x);
            acc[2] += w * bfu2f(v.y);  acc[3] += w * bfhi2f(v.y);
            acc[4] += w * bfu2f(v.z);  acc[5] += w * bfhi2f(v.z);
            acc[6] += w * bfu2f(v.w);  acc[7] += w * bfhi2f(v.w);
        }
    }
#pragma unroll
    for (int i = 0; i < 8; ++i) {
        acc[i] += __shfl_xor(acc[i], 16, 64);
        acc[i] += __shfl_xor(acc[i], 32, 64);
    }
    if (g == 0) {
        uint4 v = *(const uint4*)(Xb + (size_t)node * 64 + col);  // self row (pre-scaled)
        acc[0] += bfu2f(v.x);  acc[1] += bfhi2f(v.x);
        acc[2] += bfu2f(v.y);  acc[3] += bfhi2f(v.y);
        acc[4] += bfu2f(v.z);  acc[5] += bfhi2f(v.z);
        acc[6] += bfu2f(v.w);  acc[7] += bfhi2f(v.w);
        float wd = dinv[node];
        float* po = outf + (size_t)node * 128 + l * 8;
        *(float4*)(po)     = make_float4(wd * acc[0], wd * acc[1], wd * acc[2], wd * acc[3]);
        *(float4*)(po + 4) = make_float4(wd * acc[4], wd * acc[5], wd * acc[6], wd * acc[7]);
    }
}

// ---------------- MFMA GEMM: out = relu(A_f32 @ W + b), split-precision bf16 ----
// D = Ah*Wh + Al*Wh + Ah*Wl. Wave: 16 rows x 128 cols; block = 64 rows. No LDS.
template <bool SCALED_BF16>
__global__ __launch_bounds__(256) void k_gemm_mfma(const float* __restrict__ A,
                                                   const unsigned short* __restrict__ Wh,
                                                   const unsigned short* __restrict__ Wl,
                                                   const float* __restrict__ bias,
                                                   const float* __restrict__ dinv,
                                                   void* __restrict__ out, int n) {
    int t = threadIdx.x;
    int wv = t >> 6, lane = t & 63;
    int quad = lane >> 4, l16 = lane & 15;
    int rowBase = blockIdx.x * 64 + wv * 16;
    int m = rowBase + l16;
    size_t arow = (size_t)min(m, n - 1) * 128;
    bool mok = m < n;

    floatx4 acc[8];
#pragma unroll
    for (int c = 0; c < 8; ++c) acc[c] = (floatx4){0.f, 0.f, 0.f, 0.f};

#pragma unroll
    for (int kk = 0; kk < 4; ++kk) {
        const float* ap = A + arow + kk * 32 + quad * 8;
        float4 a0 = mok ? *(const float4*)(ap) : make_float4(0.f, 0.f, 0.f, 0.f);
        float4 a1 = mok ? *(const float4*)(ap + 4) : make_float4(0.f, 0.f, 0.f, 0.f);
        float av[8] = {a0.x, a0.y, a0.z, a0.w, a1.x, a1.y, a1.z, a1.w};
        short8 ah, al;
#pragma unroll
        for (int j = 0; j < 8; ++j) {
            unsigned short h = f2bfu(av[j]);
            ah[j] = (short)h;
            al[j] = (short)f2bfu(av[j] - bfu2f(h));
        }
#pragma unroll
        for (int c = 0; c < 8; ++c) {
            int fo = ((c * 4 + kk) * 64 + lane) * 8;
            short8 bh = *(const short8*)(Wh + fo);
            short8 bl = *(const short8*)(Wl + fo);
            acc[c] = __builtin_amdgcn_mfma_f32_16x16x32_bf16(ah, bh, acc[c], 0, 0, 0);
            acc[c] = __builtin_amdgcn_mfma_f32_16x16x32_bf16(al, bh, acc[c], 0, 0, 0);
            acc[c] = __builtin_amdgcn_mfma_f32_16x16x32_bf16(ah, bl, acc[c], 0, 0, 0);
        }
    }

    // epilogue: C/D layout col = lane&15, row = quad*4 + reg  [m89-verified]
#pragma unroll
    for (int c = 0; c < 8; ++c) {
        int ncol = c * 16 + l16;
        float bv = bias[ncol];
#pragma unroll
        for (int r = 0; r < 4; ++r) {
            int row = rowBase + quad * 4 + r;
            if (row < n) {
                float o = fmaxf(acc[c][r] + bv, 0.f);
                if constexpr (SCALED_BF16) {
                    ((unsigned short*)out)[(size_t)row * 128 + ncol] = f2bfu(o * dinv[row]);
                } else {
                    ((float*)out)[(size_t)row * 128 + ncol] = o;
                }
            }
        }
    }
}

extern "C" void kernel_launch(void* const* d_in, const int* in_sizes, int n_in,
                              void* d_out, int out_size, void* d_ws, size_t ws_size,
                              hipStream_t stream) {
    const int n = in_sizes[0] / 128;
    const int e = in_sizes[1] / 2;
    const void* x = d_in[0];
    const int* ei = (const int*)d_in[1];

    char* w = (char*)d_ws;
    size_t o = 0;
    auto alloc = [&](size_t bytes) -> char* {
        char* p = w + o;
        o += (bytes + 255) & ~(size_t)255;
        return p;
    };
    const int nb = (n + 255) / 256;  // scan blocks
    int* flagE = (int*)alloc(4);
    int* flagX = (int*)alloc(4);
    int* cnt   = (int*)alloc((size_t)n * 4);
    int* off   = (int*)alloc((size_t)(n + 1) * 4);
    int* cur   = (int*)alloc((size_t)n * 4);
    float* dinv  = (float*)alloc((size_t)n * 4);
    int* part  = (int*)alloc((size_t)nb * 4);
    int* ppre  = (int*)alloc((size_t)nb * 4);
    int* csrc  = (int*)alloc((size_t)e * 4);  // 4B edge records
    unsigned short* W1h = (unsigned short*)alloc(16384 * 2);
    unsigned short* W1l = (unsigned short*)alloc(16384 * 2);
    unsigned short* W2h = (unsigned short*)alloc(16384 * 2);
    unsigned short* W2l = (unsigned short*)alloc(16384 * 2);
    float* bf1 = (float*)alloc(128 * 4);
    float* bf2 = (float*)alloc(128 * 4);
    unsigned int* Xb = (unsigned int*)alloc((size_t)n * 64 * 4);  // pre-scaled bf16 table
    float* B1 = (float*)alloc((size_t)n * 128 * 4);               // fp32 agg output
    (void)ws_size;  // ~42 MB

    k_prep<<<256, 256, 0, stream>>>(x, ei, d_in[2], d_in[3], d_in[4], d_in[5],
                                    flagE, flagX, cnt, W1h, W1l, W2h, W2l, bf1, bf2, n);
    const int rpx = (n + 7) / 8;               // dst-range per XCD
    int ecx = ((e + 255) / 256) * 8;           // 8 range-blocks per edge chunk
    k_count<<<ecx, 256, 0, stream>>>(ei, flagE, cnt, e, n, rpx);
    k_bsum<<<nb, 256, 0, stream>>>(cnt, part, n);
    k_pscan<<<1, 64, 0, stream>>>(part, ppre, nb);
    k_bscan<<<nb, 256, 0, stream>>>(cnt, ppre, off, cur, dinv, n);
    k_fill<<<ecx, 256, 0, stream>>>(ei, flagE, cur, csrc, e, n, rpx);
    k_scale<<<2048, 256, 0, stream>>>(x, flagX, dinv, Xb, n);

    int gm = (n + 63) / 64;
    int ga = (n + 3) / 4;
    // layer 1: B1 = dinv*(agg Xb); Xb <- bf16(dinv * relu(B1 @ W1 + b1))
    k_agg<<<ga, 256, 0, stream>>>(Xb, off, csrc, dinv, B1, n);
    k_gemm_mfma<true><<<gm, 256, 0, stream>>>(B1, W1h, W1l, bf1, dinv, Xb, n);
    // layer 2: B1 = dinv*(agg Xb); d_out(fp32) = relu(B1 @ W2 + b2)
    k_agg<<<ga, 256, 0, stream>>>(Xb, off, csrc, dinv, B1, n);
    k_gemm_mfma<false><<<gm, 256, 0, stream>>>(B1, W2h, W2l, bf2, dinv, d_out, n);
}

// Round 13
// 280.383 us; speedup vs baseline: 1.0647x; 1.0101x over previous
//
#include <hip/hip_runtime.h>
#include <hip/hip_bf16.h>

typedef __hip_bfloat16 bf16h;
typedef short short8 __attribute__((ext_vector_type(8)));
typedef float floatx4 __attribute__((ext_vector_type(4)));

__device__ __forceinline__ float bfu2f(unsigned int u) {
    return __uint_as_float((u & 0xffffu) << 16);
}
__device__ __forceinline__ float bfhi2f(unsigned int u) {
    return __uint_as_float(u & 0xffff0000u);
}
__device__ __forceinline__ unsigned short f2bfu(float f) {
    bf16h b = __float2bfloat16(f);  // RNE
    return *(unsigned short*)&b;
}

// ---------------- prep: detect dtypes, zero cnt, W -> MFMA bf16 hi/lo fragments,
//                  bias fp32, x -> UNSCALED bf16 gather table ----
__global__ __launch_bounds__(256) void k_prep(const void* __restrict__ x,
                                              const int* __restrict__ ei,
                                              const void* __restrict__ W1, const void* __restrict__ b1,
                                              const void* __restrict__ W2, const void* __restrict__ b2,
                                              int* __restrict__ flagE,
                                              int* __restrict__ cnt,
                                              unsigned short* __restrict__ W1h, unsigned short* __restrict__ W1l,
                                              unsigned short* __restrict__ W2h, unsigned short* __restrict__ W2l,
                                              float* __restrict__ bfv1, float* __restrict__ bfv2,
                                              unsigned int* __restrict__ Xb, int n) {
    int t = threadIdx.x;
    __shared__ int sIsB;
    if (t < 64) {  // per-block local bf16-vs-fp32 detection on x
        unsigned int w = ((const unsigned int*)x)[t];
        unsigned int ef = (w >> 7) & 0xFFu;
        unsigned long long b = __ballot(ef >= 0x76u && ef <= 0x82u);
        if (t == 0) sIsB = (__popcll(b) >= 40) ? 1 : 0;
    }
    __syncthreads();
    bool isb = sIsB != 0;

    if (blockIdx.x == 0 && t < 64) {  // edge dtype: int64 => all odd words zero
        int v = ei[2 * t + 1];
        unsigned long long b = __ballot(v == 0);
        if (t == 0) *flagE = (b == ~0ull) ? 1 : 0;
    }

    int gsz = gridDim.x * 256;
    int gid = blockIdx.x * 256 + t;
    for (int i = gid; i < n; i += gsz) cnt[i] = 0;
    for (int i = gid; i < 16384; i += gsz) {
        int c  = i >> 11;
        int kk = (i >> 9) & 3;
        int ln = (i >> 3) & 63;
        int j  = i & 7;
        int k    = kk * 32 + (ln >> 4) * 8 + j;
        int ncol = c * 16 + (ln & 15);
        int src  = k * 128 + ncol;
        float v1 = isb ? bfu2f(((const unsigned short*)W1)[src]) : ((const float*)W1)[src];
        float v2 = isb ? bfu2f(((const unsigned short*)W2)[src]) : ((const float*)W2)[src];
        unsigned short h1 = f2bfu(v1), h2 = f2bfu(v2);
        W1h[i] = h1; W1l[i] = f2bfu(v1 - bfu2f(h1));
        W2h[i] = h2; W2l[i] = f2bfu(v2 - bfu2f(h2));
    }
    if (gid < 128) {
        bfv1[gid] = isb ? bfu2f(((const unsigned short*)b1)[gid]) : ((const float*)b1)[gid];
        bfv2[gid] = isb ? bfu2f(((const unsigned short*)b2)[gid]) : ((const float*)b2)[gid];
    }
    int total = n * 64;  // packed bf16 pairs, unscaled
    if (isb) {
        const unsigned int* xs = (const unsigned int*)x;
        for (int i = gid; i < total; i += gsz) Xb[i] = xs[i];
    } else {
        const float2* xf = (const float2*)x;
        for (int i = gid; i < total; i += gsz) {
            float2 v = xf[i];
            Xb[i] = ((unsigned int)f2bfu(v.y) << 16) | f2bfu(v.x);
        }
    }
}

// ---------------- CSR build, XCD dst-partitioned (R12-proven) ----------------

__global__ void k_count(const int* __restrict__ ei, const int* __restrict__ flag,
                        int* __restrict__ cnt, int e, int n, int rpx) {
    int xcd = blockIdx.x & 7;
    int i = (blockIdx.x >> 3) * 256 + threadIdx.x;
    if (i >= e) return;
    int st = (*flag) ? 2 : 1;
    int d = ei[(size_t)e * st + (size_t)i * st];
    int lo = xcd * rpx, hi = min(n, lo + rpx);
    if (d >= lo && d < hi) atomicAdd(&cnt[d], 1);
}

// scan phase 1: per-block (256-elem) partial sums
__global__ __launch_bounds__(256) void k_bsum(const int* __restrict__ cnt,
                                              int* __restrict__ part, int n) {
    int t = threadIdx.x;
    int i = blockIdx.x * 256 + t;
    int v = (i < n) ? cnt[i] : 0;
#pragma unroll
    for (int m = 1; m < 64; m <<= 1) v += __shfl_xor(v, m, 64);
    __shared__ int ws[4];
    if ((t & 63) == 0) ws[t >> 6] = v;
    __syncthreads();
    if (t == 0) part[blockIdx.x] = ws[0] + ws[1] + ws[2] + ws[3];
}

// scan phase 2: single-wave exclusive scan over nb partials
__global__ void k_pscan(const int* __restrict__ part, int* __restrict__ ppre, int nb) {
    int lane = threadIdx.x;  // 64 threads
    int carry = 0;
    for (int base = 0; base < nb; base += 64) {
        int i = base + lane;
        int v = (i < nb) ? part[i] : 0;
        int incl = v;
#pragma unroll
        for (int d = 1; d < 64; d <<= 1) {
            int u = __shfl_up(incl, d, 64);
            if (lane >= d) incl += u;
        }
        if (i < nb) ppre[i] = carry + incl - v;
        carry += __shfl(incl, 63, 64);
    }
}

// scan phase 3: block-local scan + prefix, write off/cur/dinv (+off[n])
__global__ __launch_bounds__(256) void k_bscan(const int* __restrict__ cnt,
                                               const int* __restrict__ ppre,
                                               int* __restrict__ off, int* __restrict__ cur,
                                               float* __restrict__ dinv, int n) {
    int t = threadIdx.x;
    int lane = t & 63, wid = t >> 6;
    int i = blockIdx.x * 256 + t;
    int v = (i < n) ? cnt[i] : 0;
    int incl = v;
#pragma unroll
    for (int d = 1; d < 64; d <<= 1) {
        int u = __shfl_up(incl, d, 64);
        if (lane >= d) incl += u;
    }
    __shared__ int ws[4], wo[4];
    if (lane == 63) ws[wid] = incl;
    __syncthreads();
    if (t == 0) {
        int s = 0;
#pragma unroll
        for (int k = 0; k < 4; ++k) { wo[k] = s; s += ws[k]; }
    }
    __syncthreads();
    int excl = ppre[blockIdx.x] + wo[wid] + incl - v;
    if (i < n) {
        off[i] = excl;
        cur[i] = excl;
        dinv[i] = rsqrtf((float)v + 1.0f);
        if (i == n - 1) off[n] = excl + v;
    }
}

// XCD dst-partitioned fill; 4B record (src only)
__global__ void k_fill(const int* __restrict__ ei, const int* __restrict__ flag,
                       int* __restrict__ cur, int* __restrict__ csrc,
                       int e, int n, int rpx) {
    int xcd = blockIdx.x & 7;
    int i = (blockIdx.x >> 3) * 256 + threadIdx.x;
    if (i >= e) return;
    int st = (*flag) ? 2 : 1;
    int d = ei[(size_t)e * st + (size_t)i * st];
    int lo = xcd * rpx, hi = min(n, lo + rpx);
    if (d < lo || d >= hi) return;
    int s = ei[(size_t)i * st];
    if (s < 0 || s >= n) return;
    int pos = atomicAdd(&cur[d], 1);
    csrc[pos] = s;
}

// ---------------- Aggregate: out[v] = dinv[v]*(sum_s dinv[s]*Xb[s] + dinv[v]*Xb[v]) ----
// One wave/node; 4 groups x 16 lanes; uint4/lane (full 256B row per group);
// 16 rows in flight per wave. dinv[s] via broadcast scalar load (L2-hot 200KB).
__global__ __launch_bounds__(256) void k_agg(const unsigned int* __restrict__ Xb,
                                             const int* __restrict__ off,
                                             const int* __restrict__ csrc,
                                             const float* __restrict__ dinv,
                                             float* __restrict__ outf, int n) {
    int node = blockIdx.x * 4 + (threadIdx.x >> 6);
    if (node >= n) return;
    int lane = threadIdx.x & 63;
    int g = lane >> 4;    // group 0..3
    int l = lane & 15;    // lane in group
    int col = l * 4;      // uint index: 16 lanes x uint4 = full 128-feature row
    int beg = off[node], end = off[node + 1];
    int nm1 = n - 1;
    float acc[8] = {0.f, 0.f, 0.f, 0.f, 0.f, 0.f, 0.f, 0.f};
    for (int j = beg; j < end; j += 16) {
#pragma unroll
        for (int k = 0; k < 4; ++k) {
            int jj = j + k * 4 + g;
            bool ok = jj < end;
            int s = ok ? csrc[jj] : node;
            s = min(max(s, 0), nm1);
            float w = ok ? dinv[s] : 0.f;
            uint4 v = *(const uint4*)(Xb + (size_t)s * 64 + col);
            acc[0] += w * bfu2f(v.x);  acc[1] += w * bfhi2f(v.x);
            acc[2] += w * bfu2f(v.y);  acc[3] += w * bfhi2f(v.y);
            acc[4] += w * bfu2f(v.z);  acc[5] += w * bfhi2f(v.z);
            acc[6] += w * bfu2f(v.w);  acc[7] += w * bfhi2f(v.w);
        }
    }
#pragma unroll
    for (int i = 0; i < 8; ++i) {
        acc[i] += __shfl_xor(acc[i], 16, 64);
        acc[i] += __shfl_xor(acc[i], 32, 64);
    }
    if (g == 0) {
        float wd = dinv[node];
        uint4 v = *(const uint4*)(Xb + (size_t)node * 64 + col);  // self row
        acc[0] += wd * bfu2f(v.x);  acc[1] += wd * bfhi2f(v.x);
        acc[2] += wd * bfu2f(v.y);  acc[3] += wd * bfhi2f(v.y);
        acc[4] += wd * bfu2f(v.z);  acc[5] += wd * bfhi2f(v.z);
        acc[6] += wd * bfu2f(v.w);  acc[7] += wd * bfhi2f(v.w);
        float* po = outf + (size_t)node * 128 + l * 8;
        *(float4*)(po)     = make_float4(wd * acc[0], wd * acc[1], wd * acc[2], wd * acc[3]);
        *(float4*)(po + 4) = make_float4(wd * acc[4], wd * acc[5], wd * acc[6], wd * acc[7]);
    }
}

// ---------------- MFMA GEMM: out = relu(A_f32 @ W + b), split-precision bf16 ----
// D = Ah*Wh + Al*Wh + Ah*Wl. Wave: 16 rows x 128 cols; block = 64 rows. No LDS.
template <bool OUT_BF16>
__global__ __launch_bounds__(256) void k_gemm_mfma(const float* __restrict__ A,
                                                   const unsigned short* __restrict__ Wh,
                                                   const unsigned short* __restrict__ Wl,
                                                   const float* __restrict__ bias,
                                                   void* __restrict__ out, int n) {
    int t = threadIdx.x;
    int wv = t >> 6, lane = t & 63;
    int quad = lane >> 4, l16 = lane & 15;
    int rowBase = blockIdx.x * 64 + wv * 16;
    int m = rowBase + l16;
    size_t arow = (size_t)min(m, n - 1) * 128;
    bool mok = m < n;

    floatx4 acc[8];
#pragma unroll
    for (int c = 0; c < 8; ++c) acc[c] = (floatx4){0.f, 0.f, 0.f, 0.f};

#pragma unroll
    for (int kk = 0; kk < 4; ++kk) {
        const float* ap = A + arow + kk * 32 + quad * 8;
        float4 a0 = mok ? *(const float4*)(ap) : make_float4(0.f, 0.f, 0.f, 0.f);
        float4 a1 = mok ? *(const float4*)(ap + 4) : make_float4(0.f, 0.f, 0.f, 0.f);
        float av[8] = {a0.x, a0.y, a0.z, a0.w, a1.x, a1.y, a1.z, a1.w};
        short8 ah, al;
#pragma unroll
        for (int j = 0; j < 8; ++j) {
            unsigned short h = f2bfu(av[j]);
            ah[j] = (short)h;
            al[j] = (short)f2bfu(av[j] - bfu2f(h));
        }
#pragma unroll
        for (int c = 0; c < 8; ++c) {
            int fo = ((c * 4 + kk) * 64 + lane) * 8;
            short8 bh = *(const short8*)(Wh + fo);
            short8 bl = *(const short8*)(Wl + fo);
            acc[c] = __builtin_amdgcn_mfma_f32_16x16x32_bf16(ah, bh, acc[c], 0, 0, 0);
            acc[c] = __builtin_amdgcn_mfma_f32_16x16x32_bf16(al, bh, acc[c], 0, 0, 0);
            acc[c] = __builtin_amdgcn_mfma_f32_16x16x32_bf16(ah, bl, acc[c], 0, 0, 0);
        }
    }

    // epilogue: C/D layout col = lane&15, row = quad*4 + reg  [m89-verified]
#pragma unroll
    for (int c = 0; c < 8; ++c) {
        int ncol = c * 16 + l16;
        float bv = bias[ncol];
#pragma unroll
        for (int r = 0; r < 4; ++r) {
            int row = rowBase + quad * 4 + r;
            if (row < n) {
                float o = fmaxf(acc[c][r] + bv, 0.f);
                if constexpr (OUT_BF16) {
                    ((unsigned short*)out)[(size_t)row * 128 + ncol] = f2bfu(o);
                } else {
                    ((float*)out)[(size_t)row * 128 + ncol] = o;
                }
            }
        }
    }
}

extern "C" void kernel_launch(void* const* d_in, const int* in_sizes, int n_in,
                              void* d_out, int out_size, void* d_ws, size_t ws_size,
                              hipStream_t stream) {
    const int n = in_sizes[0] / 128;
    const int e = in_sizes[1] / 2;
    const void* x = d_in[0];
    const int* ei = (const int*)d_in[1];

    char* w = (char*)d_ws;
    size_t o = 0;
    auto alloc = [&](size_t bytes) -> char* {
        char* p = w + o;
        o += (bytes + 255) & ~(size_t)255;
        return p;
    };
    const int nb = (n + 255) / 256;  // scan blocks
    int* flagE = (int*)alloc(4);
    int* cnt   = (int*)alloc((size_t)n * 4);
    int* off   = (int*)alloc((size_t)(n + 1) * 4);
    int* cur   = (int*)alloc((size_t)n * 4);
    float* dinv  = (float*)alloc((size_t)n * 4);
    int* part  = (int*)alloc((size_t)nb * 4);
    int* ppre  = (int*)alloc((size_t)nb * 4);
    int* csrc  = (int*)alloc((size_t)e * 4);  // 4B edge records
    unsigned short* W1h = (unsigned short*)alloc(16384 * 2);
    unsigned short* W1l = (unsigned short*)alloc(16384 * 2);
    unsigned short* W2h = (unsigned short*)alloc(16384 * 2);
    unsigned short* W2l = (unsigned short*)alloc(16384 * 2);
    float* bf1 = (float*)alloc(128 * 4);
    float* bf2 = (float*)alloc(128 * 4);
    unsigned int* Xb = (unsigned int*)alloc((size_t)n * 64 * 4);  // unscaled bf16 table
    float* B1 = (float*)alloc((size_t)n * 128 * 4);               // fp32 agg output
    (void)ws_size;  // ~42 MB

    k_prep<<<1024, 256, 0, stream>>>(x, ei, d_in[2], d_in[3], d_in[4], d_in[5],
                                     flagE, cnt, W1h, W1l, W2h, W2l, bf1, bf2, Xb, n);
    const int rpx = (n + 7) / 8;               // dst-range per XCD
    int ecx = ((e + 255) / 256) * 8;           // 8 range-blocks per edge chunk
    k_count<<<ecx, 256, 0, stream>>>(ei, flagE, cnt, e, n, rpx);
    k_bsum<<<nb, 256, 0, stream>>>(cnt, part, n);
    k_pscan<<<1, 64, 0, stream>>>(part, ppre, nb);
    k_bscan<<<nb, 256, 0, stream>>>(cnt, ppre, off, cur, dinv, n);
    k_fill<<<ecx, 256, 0, stream>>>(ei, flagE, cur, csrc, e, n, rpx);

    int gm = (n + 63) / 64;
    int ga = (n + 3) / 4;
    // layer 1: B1 = dinv*(agg dinv*Xb); Xb <- bf16(relu(B1 @ W1 + b1))
    k_agg<<<ga, 256, 0, stream>>>(Xb, off, csrc, dinv, B1, n);
    k_gemm_mfma<true><<<gm, 256, 0, stream>>>(B1, W1h, W1l, bf1, Xb, n);
    // layer 2: B1 = dinv*(agg dinv*Xb); d_out(fp32) = relu(B1 @ W2 + b2)
    k_agg<<<ga, 256, 0, stream>>>(Xb, off, csrc, dinv, B1, n);
    k_gemm_mfma<false><<<gm, 256, 0, stream>>>(B1, W2h, W2l, bf2, d_out, n);
}